// Round 7
// baseline (129.458 us; speedup 1.0000x reference)
//
#include <hip/hip_runtime.h>

// IRNN 8-direction scan. x: [8,32,256,256] f32. Outputs (concat order):
// 0 up, 1 right, 2 down, 3 left, 4 zuoxia, 5 youxia, 6 zuoshang(==zuoxia), 7 youshang.
//
// Round-7: R6 (nt stores, 124.8us) with ONE change: merge the two kernels so
// vertical (latency-heavy) and horizontal (store-burst-heavy) waves co-reside
// (13 waves/CU) and overlap. Horizontal uses the R5-verified in-place single
// LDS buffer (8.4 KiB -> 13 blocks/CU fit under the 160 KiB LDS cap).
//   [0,1280)    vertical: role=bid>>8: 0 down(out2) 1 up(out0)
//               2 zuoxia(out4+out6) 3 youxia(out5) 4 youshang(out7)
//   [1280,2304) horizontal right -> out1
//   [2304,3328) horizontal left  -> out3

namespace {
constexpr int HH = 256;
constexpr int WW = 256;
constexpr int PLANE = HH * WW;
constexpr size_t TEN = (size_t)PLANE * 256;

__device__ __forceinline__ float relu_f(float a) { return fmaxf(a, 0.0f); }

typedef float v4f __attribute__((ext_vector_type(4)));

__device__ __forceinline__ void nt_store4(float* p, const float4& v) {
    v4f t; t.x = v.x; t.y = v.y; t.z = v.z; t.w = v.w;
    __builtin_nontemporal_store(t, (v4f*)p);
}
} // namespace

__global__ __launch_bounds__(64) void irnn_all(
    const float* __restrict__ x, float* __restrict__ out,
    const float* __restrict__ wup_p, const float* __restrict__ wdn_p,
    const float* __restrict__ wlf_p, const float* __restrict__ wrt_p)
{
    __shared__ float xs[64][33];   // horizontal blocks only; 8.4 KiB

    const int bid = blockIdx.x;
    const int t = threadIdx.x;

    if (bid < 1280) {
        const int role = bid >> 8;
        const int plane = bid & 255;
        const float* xp = x + (size_t)plane * PLANE + t * 4;

        if (role == 0) {                 // down -> out2
            const float wd = *wdn_p;
            float* op = out + 2 * TEN + (size_t)plane * PLANE + t * 4;
            float4 c = *(const float4*)xp;
            nt_store4(op, c);
            for (int h = 1; h < HH; ++h) {
                float4 v = *(const float4*)(xp + h * WW);
                c.x = relu_f(c.x * wd + v.x);
                c.y = relu_f(c.y * wd + v.y);
                c.z = relu_f(c.z * wd + v.z);
                c.w = relu_f(c.w * wd + v.w);
                nt_store4(op + h * WW, c);
            }
        } else if (role == 1) {          // up -> out0
            const float wu = *wup_p;
            float* op = out + 0 * TEN + (size_t)plane * PLANE + t * 4;
            float4 c = *(const float4*)(xp + (HH - 1) * WW);
            nt_store4(op + (HH - 1) * WW, c);
            for (int h = HH - 2; h >= 0; --h) {
                float4 v = *(const float4*)(xp + h * WW);
                c.x = relu_f(c.x * wu + v.x);
                c.y = relu_f(c.y * wu + v.y);
                c.z = relu_f(c.z * wu + v.z);
                c.w = relu_f(c.w * wu + v.w);
                nt_store4(op + h * WW, c);
            }
        } else if (role == 2) {          // zuoxia -> out4 + out6
            const float wd = *wdn_p;
            float* o4 = out + 4 * TEN + (size_t)plane * PLANE + t * 4;
            float* o6 = out + 6 * TEN + (size_t)plane * PLANE + t * 4;
            float4 c = *(const float4*)xp;
            nt_store4(o4, c);
            nt_store4(o6, c);
            for (int h = 1; h < HH; ++h) {
                float4 v = *(const float4*)(xp + h * WW);
                float pw = __shfl_up(c.w, 1);
                float4 n;
                n.x = (t == 0) ? v.x : relu_f(pw * wd + v.x);
                n.y = relu_f(c.x * wd + v.y);
                n.z = relu_f(c.y * wd + v.z);
                n.w = relu_f(c.z * wd + v.w);
                nt_store4(o4 + h * WW, n);
                nt_store4(o6 + h * WW, n);
                c = n;
            }
        } else if (role == 3) {          // youxia -> out5
            const float wd = *wdn_p;
            float* o5 = out + 5 * TEN + (size_t)plane * PLANE + t * 4;
            float4 c = *(const float4*)xp;
            nt_store4(o5, c);
            for (int h = 1; h < HH; ++h) {
                float4 v = *(const float4*)(xp + h * WW);
                float nx = __shfl_down(c.x, 1);
                float4 n;
                n.x = relu_f(c.y * wd + v.x);
                n.y = relu_f(c.z * wd + v.y);
                n.z = relu_f(c.w * wd + v.z);
                n.w = (t == 63) ? v.w : relu_f(nx * wd + v.w);
                nt_store4(o5 + h * WW, n);
                c = n;
            }
        } else {                         // youshang -> out7
            const float wd = *wdn_p;
            float* o7 = out + 7 * TEN + (size_t)plane * PLANE + t * 4;
            float4 c = *(const float4*)(xp + (HH - 1) * WW);
            nt_store4(o7 + (HH - 1) * WW, c);
            for (int h = HH - 2; h >= 0; --h) {
                float4 v = *(const float4*)(xp + h * WW);
                float pw = __shfl_up(c.w, 1);
                float4 n;
                n.x = (t == 0) ? v.x : relu_f(pw * wd + v.x);
                n.y = relu_f(c.x * wd + v.y);
                n.z = relu_f(c.y * wd + v.z);
                n.w = relu_f(c.z * wd + v.w);
                nt_store4(o7 + h * WW, n);
                c = n;
            }
        }
    } else {
        // ---- horizontal: right (out1) / left (out3), 64 rows/block ----
        const int hb = bid - 1280;
        const int dir = hb >> 10;
        const int rb = hb & 1023;
        const size_t row0 = (size_t)rb * 64;
        const int lrow = t >> 3;
        const int lcol = (t & 7) * 4;

        const float w = dir ? *wlf_p : *wrt_p;
        float* op = out + (size_t)(dir ? 3 : 1) * TEN;

        float carry = 0.0f;
        for (int ci = 0; ci < 8; ++ci) {
            const int cw = dir ? (7 - ci) : ci;
            const int wbase = cw * 32;

            for (int p = 0; p < 8; ++p) {
                const int r = p * 8 + lrow;
                float4 v = *(const float4*)(x + (row0 + r) * WW + wbase + lcol);
                *(float4*)&xs[r][lcol] = v;
            }
            __syncthreads();

            if (dir == 0) {
                for (int j = 0; j < 32; ++j) {
                    const float v = xs[t][j];
                    const int wg = wbase + j;
                    const float o = (wg == 0) ? v : relu_f(carry * w + v);
                    carry = o;
                    xs[t][j] = o;          // in-place: thread owns row t
                }
            } else {
                for (int j = 31; j >= 0; --j) {
                    const float v = xs[t][j];
                    const int wg = wbase + j;
                    const float o = (wg == WW - 1) ? v : relu_f(carry * w + v);
                    carry = o;
                    xs[t][j] = o;
                }
            }
            __syncthreads();

            for (int p = 0; p < 8; ++p) {
                const int r = p * 8 + lrow;
                float4 v = *(const float4*)&xs[r][lcol];
                nt_store4(op + (row0 + r) * WW + wbase + lcol, v);
            }
            __syncthreads();
        }
    }
}

extern "C" void kernel_launch(void* const* d_in, const int* in_sizes, int n_in,
                              void* d_out, int out_size, void* d_ws, size_t ws_size,
                              hipStream_t stream) {
    const float* x      = (const float*)d_in[0];
    const float* w_up   = (const float*)d_in[1];
    const float* w_down = (const float*)d_in[2];
    const float* w_left = (const float*)d_in[3];
    const float* w_right= (const float*)d_in[4];
    float* out = (float*)d_out;

    hipLaunchKernelGGL(irnn_all, dim3(3328), dim3(64), 0, stream,
                       x, out, w_up, w_down, w_left, w_right);
}

// Round 8
// 126.163 us; speedup vs baseline: 1.0261x; 1.0261x over previous
//
#include <hip/hip_runtime.h>

// IRNN 8-direction scan. x: [8,32,256,256] f32. Outputs (concat order):
// 0 up, 1 right, 2 down, 3 left, 4 zuoxia, 5 youxia, 6 zuoshang(==zuoxia), 7 youshang.
//
// Round-8: R6 base (two kernels + nt stores, 124.8us) + ONE change:
// depth-8 register prefetch in the vertical roles (hide ~900cy HBM-miss
// latency on x rows, which the harness's 537MB out-poison evicts from L3).
// Static indexing throughout (30 groups of 8 + static 15-row tail).

namespace {
constexpr int HH = 256;
constexpr int WW = 256;
constexpr int PLANE = HH * WW;
constexpr size_t TEN = (size_t)PLANE * 256;

__device__ __forceinline__ float relu_f(float a) { return fmaxf(a, 0.0f); }

typedef float v4f __attribute__((ext_vector_type(4)));

__device__ __forceinline__ void nt_store4(float* p, const float4& v) {
    v4f t; t.x = v.x; t.y = v.y; t.z = v.z; t.w = v.w;
    __builtin_nontemporal_store(t, (v4f*)p);
}

__device__ __forceinline__ float4 ld4(const float* p) {
    return *(const float4*)p;
}

// Forward scan rows 1..255 with depth-8 prefetch; step(r, v) consumes row r.
template <typename F>
__device__ __forceinline__ void scan_fwd(const float* xp, F&& step) {
    float4 buf[8];
    #pragma unroll
    for (int k = 0; k < 8; ++k) buf[k] = ld4(xp + (1 + k) * WW);
    #pragma unroll 1
    for (int g = 0; g < 30; ++g) {
        #pragma unroll
        for (int k = 0; k < 8; ++k) {
            const int r = 1 + 8 * g + k;
            float4 v = buf[k];
            buf[k] = ld4(xp + (r + 8) * WW);   // rows 9..248
            step(r, v);
        }
    }
    float4 t7[7];
    #pragma unroll
    for (int k = 0; k < 7; ++k) t7[k] = ld4(xp + (249 + k) * WW);
    #pragma unroll
    for (int k = 0; k < 8; ++k) step(241 + k, buf[k]);
    #pragma unroll
    for (int k = 0; k < 7; ++k) step(249 + k, t7[k]);
}

// Backward scan rows 254..0 with depth-8 prefetch; step(h, v) consumes row h.
template <typename F>
__device__ __forceinline__ void scan_bwd(const float* xp, F&& step) {
    float4 buf[8];
    #pragma unroll
    for (int k = 0; k < 8; ++k) buf[k] = ld4(xp + (254 - k) * WW);
    #pragma unroll 1
    for (int g = 0; g < 30; ++g) {
        #pragma unroll
        for (int k = 0; k < 8; ++k) {
            const int h = 254 - (8 * g + k);
            float4 v = buf[k];
            buf[k] = ld4(xp + (h - 8) * WW);   // rows 246..7
            step(h, v);
        }
    }
    float4 t7[7];
    #pragma unroll
    for (int k = 0; k < 7; ++k) t7[k] = ld4(xp + (6 - k) * WW);
    #pragma unroll
    for (int k = 0; k < 8; ++k) step(14 - k, buf[k]);
    #pragma unroll
    for (int k = 0; k < 7; ++k) step(6 - k, t7[k]);
}
} // namespace

// ---------- vertical family: one wave per (role, plane) ----------
__global__ __launch_bounds__(64) void irnn_vertical(
    const float* __restrict__ x, float* __restrict__ out,
    const float* __restrict__ wup_p, const float* __restrict__ wdn_p)
{
    const int bid = blockIdx.x;
    const int role = bid >> 8;       // 5 roles x 256 planes
    const int plane = bid & 255;
    const int t = threadIdx.x;       // lane owns columns 4t..4t+3

    const float* xp = x + (size_t)plane * PLANE + t * 4;

    if (role == 0) {                 // down -> out2
        const float wd = *wdn_p;
        float* op = out + 2 * TEN + (size_t)plane * PLANE + t * 4;
        float4 c = ld4(xp);
        nt_store4(op, c);
        scan_fwd(xp, [&](int r, float4 v) {
            c.x = relu_f(c.x * wd + v.x);
            c.y = relu_f(c.y * wd + v.y);
            c.z = relu_f(c.z * wd + v.z);
            c.w = relu_f(c.w * wd + v.w);
            nt_store4(op + r * WW, c);
        });
    } else if (role == 1) {          // up -> out0
        const float wu = *wup_p;
        float* op = out + 0 * TEN + (size_t)plane * PLANE + t * 4;
        float4 c = ld4(xp + 255 * WW);
        nt_store4(op + 255 * WW, c);
        scan_bwd(xp, [&](int h, float4 v) {
            c.x = relu_f(c.x * wu + v.x);
            c.y = relu_f(c.y * wu + v.y);
            c.z = relu_f(c.z * wu + v.z);
            c.w = relu_f(c.w * wu + v.w);
            nt_store4(op + h * WW, c);
        });
    } else if (role == 2) {          // zuoxia -> out4 + out6
        const float wd = *wdn_p;
        float* o4 = out + 4 * TEN + (size_t)plane * PLANE + t * 4;
        float* o6 = out + 6 * TEN + (size_t)plane * PLANE + t * 4;
        float4 c = ld4(xp);
        nt_store4(o4, c);
        nt_store4(o6, c);
        scan_fwd(xp, [&](int r, float4 v) {
            float pw = __shfl_up(c.w, 1);
            float4 n;
            n.x = (t == 0) ? v.x : relu_f(pw * wd + v.x);
            n.y = relu_f(c.x * wd + v.y);
            n.z = relu_f(c.y * wd + v.z);
            n.w = relu_f(c.z * wd + v.w);
            nt_store4(o4 + r * WW, n);
            nt_store4(o6 + r * WW, n);
            c = n;
        });
    } else if (role == 3) {          // youxia -> out5
        const float wd = *wdn_p;
        float* o5 = out + 5 * TEN + (size_t)plane * PLANE + t * 4;
        float4 c = ld4(xp);
        nt_store4(o5, c);
        scan_fwd(xp, [&](int r, float4 v) {
            float nx = __shfl_down(c.x, 1);
            float4 n;
            n.x = relu_f(c.y * wd + v.x);
            n.y = relu_f(c.z * wd + v.y);
            n.z = relu_f(c.w * wd + v.z);
            n.w = (t == 63) ? v.w : relu_f(nx * wd + v.w);
            nt_store4(o5 + r * WW, n);
            c = n;
        });
    } else {                         // youshang -> out7
        const float wd = *wdn_p;
        float* o7 = out + 7 * TEN + (size_t)plane * PLANE + t * 4;
        float4 c = ld4(xp + 255 * WW);
        nt_store4(o7 + 255 * WW, c);
        scan_bwd(xp, [&](int h, float4 v) {
            float pw = __shfl_up(c.w, 1);
            float4 n;
            n.x = (t == 0) ? v.x : relu_f(pw * wd + v.x);
            n.y = relu_f(c.x * wd + v.y);
            n.z = relu_f(c.y * wd + v.z);
            n.w = relu_f(c.z * wd + v.w);
            nt_store4(o7 + h * WW, n);
            c = n;
        });
    }
}

// ---------- horizontal family: right (out1) and left (out3) ----------
__global__ __launch_bounds__(64) void irnn_horizontal(
    const float* __restrict__ x, float* __restrict__ out,
    const float* __restrict__ wlf_p, const float* __restrict__ wrt_p)
{
    __shared__ float xs[64][33];
    __shared__ float os[64][33];

    const int bid = blockIdx.x;
    const int dir = bid >> 10;        // 0: right, 1: left
    const int rb  = bid & 1023;
    const size_t row0 = (size_t)rb * 64;
    const int t = threadIdx.x;
    const int lrow = t >> 3;
    const int lcol = (t & 7) * 4;

    const float w = dir ? *wlf_p : *wrt_p;
    float* op = out + (size_t)(dir ? 3 : 1) * TEN;

    float carry = 0.0f;
    for (int ci = 0; ci < 8; ++ci) {
        const int cw = dir ? (7 - ci) : ci;
        const int wbase = cw * 32;

        for (int p = 0; p < 8; ++p) {
            const int r = p * 8 + lrow;
            float4 v = *(const float4*)(x + (row0 + r) * WW + wbase + lcol);
            *(float4*)&xs[r][lcol] = v;
        }
        __syncthreads();

        if (dir == 0) {
            for (int j = 0; j < 32; ++j) {
                const float v = xs[t][j];
                const int wg = wbase + j;
                const float o = (wg == 0) ? v : relu_f(carry * w + v);
                carry = o;
                os[t][j] = o;
            }
        } else {
            for (int j = 31; j >= 0; --j) {
                const float v = xs[t][j];
                const int wg = wbase + j;
                const float o = (wg == WW - 1) ? v : relu_f(carry * w + v);
                carry = o;
                os[t][j] = o;
            }
        }
        __syncthreads();

        for (int p = 0; p < 8; ++p) {
            const int r = p * 8 + lrow;
            float4 v = *(const float4*)&os[r][lcol];
            nt_store4(op + (row0 + r) * WW + wbase + lcol, v);
        }
        __syncthreads();
    }
}

extern "C" void kernel_launch(void* const* d_in, const int* in_sizes, int n_in,
                              void* d_out, int out_size, void* d_ws, size_t ws_size,
                              hipStream_t stream) {
    const float* x      = (const float*)d_in[0];
    const float* w_up   = (const float*)d_in[1];
    const float* w_down = (const float*)d_in[2];
    const float* w_left = (const float*)d_in[3];
    const float* w_right= (const float*)d_in[4];
    float* out = (float*)d_out;

    hipLaunchKernelGGL(irnn_vertical, dim3(5 * 256), dim3(64), 0, stream,
                       x, out, w_up, w_down);
    hipLaunchKernelGGL(irnn_horizontal, dim3(2 * 1024), dim3(64), 0, stream,
                       x, out, w_left, w_right);
}